// Round 1
// 257.041 us; speedup vs baseline: 1.0281x; 1.0281x over previous
//
#include <hip/hip_runtime.h>
#include <math.h>

#define D_MODEL 512
#define NHEADS 8
#define DK 64
#define BATCH 2
#define SEQ 4096
#define NIT 32          // 2048 keys per split / 64-key tiles
// log2(e)/8 folded into Q projection: scores in log2 domain, softmax uses exp2.
#define ATTN_SCALE 0.18033688011112043f
#define SPLIT_SCALE 2048.0f
#define INV_SPLIT  (1.0f/2048.0f)

typedef _Float16 half8 __attribute__((ext_vector_type(8)));
typedef __fp16 pkhalf2 __attribute__((ext_vector_type(2)));
typedef float f32x4 __attribute__((ext_vector_type(4)));

union Pk8 { _Float16 h[8]; uint4 u; };
union Pk4 { _Float16 h[4]; uint2 u; };
union Pkz { pkhalf2 h2[2]; uint2 u; };
union Un4 { uint2 u; _Float16 h[4]; };

#if __has_builtin(__builtin_amdgcn_exp2f)
#define EXP2F __builtin_amdgcn_exp2f
#else
#define EXP2F exp2f
#endif

#define MFMA16(a, b, c) __builtin_amdgcn_mfma_f32_16x16x32_f16((a), (b), (c), 0, 0, 0)

__device__ __forceinline__ void gload_lds16(const _Float16* g, _Float16* l) {
    __builtin_amdgcn_global_load_lds(
        (const __attribute__((address_space(1))) void*)g,
        (__attribute__((address_space(3))) void*)l, 16, 0, 0);
}

// ============================================================================
// prep: fp32->fp16 for 3 activations + 4 weight hi-planes (lo plane no longer
// needed anywhere — dropped entirely).
// ============================================================================
#define ABLK 4096
#define WBLK 256
__global__ __launch_bounds__(256)
void prep(const float* __restrict__ aq, const float* __restrict__ ak,
          const float* __restrict__ av,
          const float* __restrict__ wq, const float* __restrict__ wk,
          const float* __restrict__ wv, const float* __restrict__ wo,
          _Float16* __restrict__ dq, _Float16* __restrict__ dk,
          _Float16* __restrict__ dv,
          _Float16* __restrict__ hq, _Float16* __restrict__ hk,
          _Float16* __restrict__ hv, _Float16* __restrict__ ho) {
    int gid = blockIdx.x;
    const float* src;
    _Float16* hi;
    if (gid < 3 * ABLK) {
        const int w = gid / ABLK;
        gid -= w * ABLK;
        src = w == 0 ? aq : (w == 1 ? ak : av);
        hi  = w == 0 ? dq : (w == 1 ? dk : dv);
    } else {
        int g = gid - 3 * ABLK;
        const int w = g / WBLK;
        gid = g - w * WBLK;
        src = w == 0 ? wq : (w == 1 ? wk : (w == 2 ? wv : wo));
        hi  = w == 0 ? hq : (w == 1 ? hk : (w == 2 ? hv : ho));
    }
    const int i = (gid * 256 + threadIdx.x) * 4;
    float4 v = *(const float4*)(src + i);
    Pkz h;
    h.h2[0] = __builtin_amdgcn_cvt_pkrtz(v.x, v.y);
    h.h2[1] = __builtin_amdgcn_cvt_pkrtz(v.z, v.w);
    *(uint2*)(hi + i) = h.u;
}

// ============================================================================
// QKV projection GEMM (unchanged r12): double-buffered DMA, 128x128, BK=64.
// ============================================================================
__global__ __launch_bounds__(256)
void gemm_qkv(const _Float16* __restrict__ Aq, const _Float16* __restrict__ Ak,
              const _Float16* __restrict__ Av,
              const _Float16* __restrict__ Whq, const _Float16* __restrict__ Whk,
              const _Float16* __restrict__ Whv,
              const float* __restrict__ bq, const float* __restrict__ bk,
              const float* __restrict__ bv,
              _Float16* __restrict__ Qf, _Float16* __restrict__ Kf,
              _Float16* __restrict__ Vtf) {
    const int z = blockIdx.z;
    const _Float16* A    = z == 0 ? Aq  : (z == 1 ? Ak  : Av);
    const _Float16* Wh   = z == 0 ? Whq : (z == 1 ? Whk : Whv);
    const float*    bias = z == 0 ? bq  : (z == 1 ? bk  : bv);

    __shared__ __align__(16) _Float16 sA[2][128 * 64];
    __shared__ __align__(16) _Float16 sW[2][128 * 64];

    const int t    = threadIdx.x;
    const int lane = t & 63, wave = t >> 6;
    const int col  = lane & 15, quad = lane >> 4;
    const int wm   = (wave & 1) * 64, wn = (wave >> 1) * 64;
    const int m0   = blockIdx.y * 128, n0 = blockIdx.x * 128;

    const int subrow = lane >> 3;
    const int schunk = ((lane & 7) ^ subrow) * 8;

    #define STAGE_AW(K0, BUF)                                                        \
        do {                                                                          \
            _Pragma("unroll")                                                         \
            for (int j = 0; j < 4; ++j) {                                             \
                const int rw = wave * 32 + j * 8;                                     \
                gload_lds16(A  + (size_t)(m0 + rw + subrow) * 512 + (K0) + schunk,    \
                            &sA[BUF][rw * 64]);                                       \
                gload_lds16(Wh + (size_t)(n0 + rw + subrow) * 512 + (K0) + schunk,    \
                            &sW[BUF][rw * 64]);                                       \
            }                                                                         \
        } while (0)

    f32x4 acc[4][4] = {};

    STAGE_AW(0, 0);
    for (int ck = 0; ck < 8; ++ck) {
        const int cur = ck & 1;
        __syncthreads();
        if (ck + 1 < 8) STAGE_AW((ck + 1) * 64, cur ^ 1);

        #pragma unroll
        for (int kc = 0; kc < 2; ++kc) {
            const int pos = ((kc * 4 + quad) ^ (col & 7)) * 8;
            half8 af[4], wf[4];
            #pragma unroll
            for (int mt = 0; mt < 4; ++mt)
                af[mt] = *(const half8*)&sA[cur][(wm + mt * 16 + col) * 64 + pos];
            #pragma unroll
            for (int nt = 0; nt < 4; ++nt)
                wf[nt] = *(const half8*)&sW[cur][(wn + nt * 16 + col) * 64 + pos];
            #pragma unroll
            for (int mt = 0; mt < 4; ++mt)
                #pragma unroll
                for (int nt = 0; nt < 4; ++nt)
                    acc[mt][nt] = MFMA16(af[mt], wf[nt], acc[mt][nt]);
        }
    }

    float bv4[4];
    #pragma unroll
    for (int nt = 0; nt < 4; ++nt) bv4[nt] = bias[n0 + wn + nt * 16 + col];

    if (z < 2) {
        _Float16* Out = z == 0 ? Qf : Kf;
        const float alpha = z == 0 ? ATTN_SCALE : 1.0f;
        #pragma unroll
        for (int mt = 0; mt < 4; ++mt) {
            const int m = m0 + wm + mt * 16 + quad * 4;
            #pragma unroll
            for (int nt = 0; nt < 4; ++nt) {
                const int n = n0 + wn + nt * 16 + col;
                #pragma unroll
                for (int r = 0; r < 4; ++r)
                    Out[(size_t)(m + r) * 512 + n] = (_Float16)((acc[mt][nt][r] + bv4[nt]) * alpha);
            }
        }
    } else {
        #pragma unroll
        for (int mt = 0; mt < 4; ++mt) {
            const int m = m0 + wm + mt * 16 + quad * 4;
            const int b = m >> 12, s = m & (SEQ - 1);
            #pragma unroll
            for (int nt = 0; nt < 4; ++nt) {
                const int n = n0 + wn + nt * 16 + col;
                const int hh = n >> 6, d = n & (DK - 1);
                Pk4 p;
                #pragma unroll
                for (int r = 0; r < 4; ++r)
                    p.h[r] = (_Float16)(acc[mt][nt][r] + bv4[nt]);
                *(uint2*)&Vtf[((size_t)((b * NHEADS + hh) * DK + d)) * SEQ + s] = p.u;
            }
        }
    }
}

// ============================================================================
// Flash attention, K-split x2 + shared-V inner loop.
// r13 changes:
//  (1) sV single-buffered: LDS 48 KB -> 40 KB => 4 blocks/CU => ALL 1024
//      blocks co-resident (was 3/CU: 768-block round + 256-block tail round
//      at 1 blk/CU — the measured 20% occupancy). V(it) DMA is issued at the
//      top of iteration it (right after barrier A frees sV) and drained by a
//      second __syncthreads (barrier B) after softmax, so its latency hides
//      under S-compute + softmax. K stays double-buffered.
//  (2) grid swapped to (stream, qblock): linear_id % 8 == head, pinning each
//      head's 4 K/V streams (2 MB) to one XCD L2 — K/V DMAs become L2 hits,
//      covering the shortened prefetch window.
// ============================================================================
__global__ __launch_bounds__(256)
void attn_mfma(const _Float16* __restrict__ Qf, const _Float16* __restrict__ Kf,
               const _Float16* __restrict__ Vtf,
               _Float16* __restrict__ Op0, _Float16* __restrict__ Op1,
               float2* __restrict__ Ml) {
    __shared__ __align__(16) _Float16 sK[2][64 * 64];
    __shared__ __align__(16) _Float16 sV[64 * 64];
    __shared__ __align__(16) _Float16 sP[128 * 64];   // Q staging, then 32 rows/wave P

    const int t    = threadIdx.x;
    const int lane = t & 63;
    const int wave = t >> 6;
    const int col  = lane & 15;
    const int quad = lane >> 4;

    // stream-major grid: x = h + 8*(b*2+sp)  (=> XCD = linear%8 = h), y = qblock
    const int strm = blockIdx.x;
    const int h  = strm & (NHEADS - 1);
    const int z  = strm >> 3;
    const int b  = z >> 1;
    const int sp = z & 1;
    const int q0 = blockIdx.y * 128;
    const int kBase = sp * (SEQ / 2);

    const size_t rowBase = (size_t)b * SEQ;
    const size_t vBase   = ((size_t)(b * NHEADS + h)) * DK * SEQ;

    // ---- DMA pointers; issue K tile 0 immediately (overlaps Q staging) ----
    const int subrow = lane >> 3;
    const int schunk = ((lane & 7) ^ subrow) * 8;
    const _Float16* kP[2];
    const _Float16* vP[2];
    #pragma unroll
    for (int j = 0; j < 2; ++j) {
        const int rw = wave * 16 + j * 8;
        kP[j] = Kf + (rowBase + kBase + rw + subrow) * 512 + h * 64 + schunk;
        vP[j] = Vtf + vBase + (size_t)(rw + subrow) * SEQ + kBase + schunk;
        gload_lds16(kP[j], &sK[0][rw * 64]);
        kP[j] += 64 * 512;
    }

    // ---- stage Q tile (128x64) into sP with the row XOR swizzle ----
    {
        uint4 qv[4];
        #pragma unroll
        for (int i2 = 0; i2 < 4; ++i2) {
            const int slot = t + i2 * 256;
            const int r = slot >> 3, sl = slot & 7;
            qv[i2] = *(const uint4*)(Qf + (rowBase + q0 + r) * 512 + h * 64 + sl * 8);
        }
        #pragma unroll
        for (int i2 = 0; i2 < 4; ++i2) {
            const int slot = t + i2 * 256;
            const int r = slot >> 3, sl = slot & 7;
            *(uint4*)&sP[r * 64 + (sl ^ (r & 7)) * 8] = qv[i2];
        }
    }
    __syncthreads();

    half8 qf[2][2];
    #pragma unroll
    for (int nt = 0; nt < 2; ++nt)
        #pragma unroll
        for (int kc = 0; kc < 2; ++kc)
            qf[nt][kc] = *(const half8*)&sP[(wave * 32 + nt * 16 + col) * 64 +
                                            ((kc * 4 + quad) ^ (col & 7)) * 8];
    // qf reads touch only this wave's own 32 sP rows; P writes below are to the
    // same region -> intra-wave ordering suffices, no extra barrier needed.

    _Float16* Ps = sP + wave * 32 * 64;
    const int pmsk = (col & 7) << 1;

    float m_r[2] = { -INFINITY, -INFINITY };
    float l_r[2] = { 0.0f, 0.0f };
    f32x4 of[4][2] = {};

    for (int itp = 0; itp < NIT; itp += 2) {
        #pragma unroll
        for (int cur = 0; cur < 2; ++cur) {     // compile-time cur
            const int it = itp + cur;
            __syncthreads();   // barrier A: sV free (all PV(it-1) reads done),
                               // K(it) DMA drained
            // V(it) into the single buffer — covered by S+softmax below
            #pragma unroll
            for (int j = 0; j < 2; ++j) {
                const int rw = wave * 16 + j * 8;
                gload_lds16(vP[j], &sV[rw * 64]);
                vP[j] += 64;
            }
            if (it + 1 < NIT) {
                #pragma unroll
                for (int j = 0; j < 2; ++j) {
                    const int rw = wave * 16 + j * 8;
                    gload_lds16(kP[j], &sK[cur ^ 1][rw * 64]);
                    kP[j] += 64 * 512;
                }
            }

            // ---- S^T = K · Q^T : 16 MFMA ----
            f32x4 sf[4][2] = {};
            #pragma unroll
            for (int kc = 0; kc < 2; ++kc) {
                const int pos = ((kc * 4 + quad) ^ (col & 7)) * 8;
                #pragma unroll
                for (int kt = 0; kt < 4; ++kt) {
                    half8 kf = *(const half8*)&sK[cur][(kt * 16 + col) * 64 + pos];
                    #pragma unroll
                    for (int nt = 0; nt < 2; ++nt)
                        sf[kt][nt] = MFMA16(kf, qf[nt][kc], sf[kt][nt]);
                }
            }

            if (it == 0) {      // eager scale for this split
                #pragma unroll
                for (int nt = 0; nt < 2; ++nt) {
                    float mx = sf[0][nt][0];
                    #pragma unroll
                    for (int kt = 0; kt < 4; ++kt)
                        #pragma unroll
                        for (int r = 0; r < 4; ++r)
                            mx = fmaxf(mx, sf[kt][nt][r]);
                    mx = fmaxf(mx, __shfl_xor(mx, 16));
                    mx = fmaxf(mx, __shfl_xor(mx, 32));
                    m_r[nt] = mx;
                }
            }

            // ---- fast path: P = exp2(s - m_r) into 32-row sP ----
            float lrs[2];
            #pragma unroll
            for (int nt = 0; nt < 2; ++nt) {
                float ls = 0.0f;
                #pragma unroll
                for (int kt = 0; kt < 4; ++kt) {
                    const float p0 = EXP2F(sf[kt][nt][0] - m_r[nt]);
                    const float p1 = EXP2F(sf[kt][nt][1] - m_r[nt]);
                    const float p2 = EXP2F(sf[kt][nt][2] - m_r[nt]);
                    const float p3 = EXP2F(sf[kt][nt][3] - m_r[nt]);
                    ls += (p0 + p1) + (p2 + p3);
                    Pkz z2;
                    z2.h2[0] = __builtin_amdgcn_cvt_pkrtz(p0, p1);
                    z2.h2[1] = __builtin_amdgcn_cvt_pkrtz(p2, p3);
                    *(uint2*)&Ps[(nt * 16 + col) * 64 + ((kt * 4 + quad) ^ pmsk) * 4] = z2.u;
                }
                lrs[nt] = ls;
            }

            __syncthreads();   // barrier B: drains V(it) DMA (vmcnt) before PV

            // ---- O^T += V^T · P^T : 16 MFMA, V-frags read ONCE ----
            #pragma unroll
            for (int kc = 0; kc < 2; ++kc) {
                half8 pf[2];
                #pragma unroll
                for (int nt = 0; nt < 2; ++nt)
                    pf[nt] = *(const half8*)&Ps[(nt * 16 + col) * 64 +
                                                ((kc * 8 + quad * 2) ^ pmsk) * 4];
                const int pos = ((kc * 4 + quad) ^ (col & 7)) * 8;
                #pragma unroll
                for (int dt = 0; dt < 4; ++dt) {
                    half8 vf = *(const half8*)&sV[(dt * 16 + col) * 64 + pos];
                    of[dt][0] = MFMA16(vf, pf[0], of[dt][0]);
                    of[dt][1] = MFMA16(vf, pf[1], of[dt][1]);
                }
            }

            l_r[0] += lrs[0];
            l_r[1] += lrs[1];

            // ---- rare re-center ----
            if (__any(fmaxf(lrs[0], lrs[1]) > 1024.0f)) {
                #pragma unroll
                for (int nt = 0; nt < 2; ++nt) {
                    float mx = sf[0][nt][0];
                    #pragma unroll
                    for (int kt = 0; kt < 4; ++kt)
                        #pragma unroll
                        for (int r = 0; r < 4; ++r)
                            mx = fmaxf(mx, sf[kt][nt][r]);
                    mx = fmaxf(mx, __shfl_xor(mx, 16));
                    mx = fmaxf(mx, __shfl_xor(mx, 32));
                    if (mx > m_r[nt]) {
                        const float al = EXP2F(m_r[nt] - mx);
                        l_r[nt] *= al;
                        #pragma unroll
                        for (int dt = 0; dt < 4; ++dt)
                            #pragma unroll
                            for (int r = 0; r < 4; ++r)
                                of[dt][nt][r] *= al;
                        m_r[nt] = mx;
                    }
                }
            }
        }
    }

    // ---- finalize: per-split normalized O (fp16) + (m, l) ----
    _Float16* Opx = sp ? Op1 : Op0;
    #pragma unroll
    for (int nt = 0; nt < 2; ++nt) {
        float l = l_r[nt];
        l += __shfl_xor(l, 16);
        l += __shfl_xor(l, 32);
        const float inv = 1.0f / l;
        const int q = q0 + wave * 32 + nt * 16 + col;
        const size_t R = (size_t)b * SEQ + q;
        #pragma unroll
        for (int dt = 0; dt < 4; ++dt) {
            Pkz z2;
            z2.h2[0] = __builtin_amdgcn_cvt_pkrtz(of[dt][nt][0] * inv, of[dt][nt][1] * inv);
            z2.h2[1] = __builtin_amdgcn_cvt_pkrtz(of[dt][nt][2] * inv, of[dt][nt][3] * inv);
            *(uint2*)(Opx + R * 512 + h * 64 + dt * 16 + quad * 4) = z2.u;
        }
        if (quad == 0)
            Ml[(size_t)(sp * BATCH * SEQ) * NHEADS + R * NHEADS + h] = make_float2(m_r[nt], l);
    }
}

// ============================================================================
// attn_merge: flash-combine of the two K-split partials -> Oh (hi fp16 only;
// gemm_out is now hi-only on A).
// ============================================================================
__global__ __launch_bounds__(256)
void attn_merge(const _Float16* __restrict__ Op0, const _Float16* __restrict__ Op1,
                const float2* __restrict__ Ml, _Float16* __restrict__ Oh) {
    const int i4 = (blockIdx.x * 256 + threadIdx.x) * 4;
    const int R = i4 >> 9;
    const int c = i4 & 511;
    const int h = c >> 6;

    const float2 ml1 = Ml[(size_t)R * NHEADS + h];
    const float2 ml2 = Ml[(size_t)(BATCH * SEQ) * NHEADS + (size_t)R * NHEADS + h];
    const float m = fmaxf(ml1.x, ml2.x);
    float w1 = EXP2F(ml1.x - m) * ml1.y;
    float w2 = EXP2F(ml2.x - m) * ml2.y;
    const float inv = 1.0f / (w1 + w2);
    w1 *= inv; w2 *= inv;

    Un4 a, bb;
    a.u  = *(const uint2*)(Op0 + (size_t)R * 512 + c);
    bb.u = *(const uint2*)(Op1 + (size_t)R * 512 + c);

    Pkz hh;
    hh.h2[0] = __builtin_amdgcn_cvt_pkrtz(w1 * (float)a.h[0] + w2 * (float)bb.h[0],
                                          w1 * (float)a.h[1] + w2 * (float)bb.h[1]);
    hh.h2[1] = __builtin_amdgcn_cvt_pkrtz(w1 * (float)a.h[2] + w2 * (float)bb.h[2],
                                          w1 * (float)a.h[3] + w2 * (float)bb.h[3]);
    *(uint2*)(Oh + (size_t)R * 512 + c) = hh.u;
}

// ============================================================================
// Output projection: hi-only A and W (1 MFMA/tile). Double-buffered DMA.
// Block 128x64, LDS 48 KB -> 3 blocks/CU. fp32 out + bias.
// ============================================================================
__global__ __launch_bounds__(256)
void gemm_out(const _Float16* __restrict__ Ah, const _Float16* __restrict__ Wh,
              const float* __restrict__ bias, float* __restrict__ C) {
    __shared__ __align__(16) _Float16 sAh[2][128 * 64];
    __shared__ __align__(16) _Float16 sWh[2][64 * 64];

    const int t    = threadIdx.x;
    const int lane = t & 63, wave = t >> 6;
    const int col  = lane & 15, quad = lane >> 4;
    const int wm   = (wave & 1) * 64, wn = (wave >> 1) * 32;
    const int m0   = blockIdx.y * 128, n0 = blockIdx.x * 64;

    const int subrow = lane >> 3;
    const int schunk = ((lane & 7) ^ subrow) * 8;

    #define STAGE_OUT(K0, BUF)                                                       \
        do {                                                                          \
            _Pragma("unroll")                                                         \
            for (int j = 0; j < 4; ++j) {                                             \
                const int rw = wave * 32 + j * 8;                                     \
                gload_lds16(Ah + (size_t)(m0 + rw + subrow) * 512 + (K0) + schunk,    \
                            &sAh[BUF][rw * 64]);                                      \
            }                                                                         \
            _Pragma("unroll")                                                         \
            for (int j = 0; j < 2; ++j) {                                             \
                const int rw = wave * 16 + j * 8;                                     \
                gload_lds16(Wh + (size_t)(n0 + rw + subrow) * 512 + (K0) + schunk,    \
                            &sWh[BUF][rw * 64]);                                      \
            }                                                                         \
        } while (0)

    f32x4 acc[4][2] = {};

    STAGE_OUT(0, 0);
    for (int ck = 0; ck < 8; ++ck) {
        const int cur = ck & 1;
        __syncthreads();
        if (ck + 1 < 8) STAGE_OUT((ck + 1) * 64, cur ^ 1);

        #pragma unroll
        for (int kc = 0; kc < 2; ++kc) {
            const int pos = ((kc * 4 + quad) ^ (col & 7)) * 8;
            half8 ahf[4], whf[2];
            #pragma unroll
            for (int mt = 0; mt < 4; ++mt)
                ahf[mt] = *(const half8*)&sAh[cur][(wm + mt * 16 + col) * 64 + pos];
            #pragma unroll
            for (int nt = 0; nt < 2; ++nt)
                whf[nt] = *(const half8*)&sWh[cur][(wn + nt * 16 + col) * 64 + pos];
            #pragma unroll
            for (int mt = 0; mt < 4; ++mt)
                #pragma unroll
                for (int nt = 0; nt < 2; ++nt)
                    acc[mt][nt] = MFMA16(ahf[mt], whf[nt], acc[mt][nt]);
        }
    }

    float bv2[2];
    #pragma unroll
    for (int nt = 0; nt < 2; ++nt) bv2[nt] = bias[n0 + wn + nt * 16 + col];

    #pragma unroll
    for (int mt = 0; mt < 4; ++mt) {
        const int m = m0 + wm + mt * 16 + quad * 4;
        #pragma unroll
        for (int nt = 0; nt < 2; ++nt) {
            const int n = n0 + wn + nt * 16 + col;
            #pragma unroll
            for (int r = 0; r < 4; ++r)
                C[(size_t)(m + r) * 512 + n] = acc[mt][nt][r] + bv2[nt];
        }
    }
}

// ============================================================================
extern "C" void kernel_launch(void* const* d_in, const int* in_sizes, int n_in,
                              void* d_out, int out_size, void* d_ws, size_t ws_size,
                              hipStream_t stream) {
    const float* query = (const float*)d_in[0];
    const float* key   = (const float*)d_in[1];
    const float* value = (const float*)d_in[2];
    const float* w_q   = (const float*)d_in[3];
    const float* b_q   = (const float*)d_in[4];
    const float* w_k   = (const float*)d_in[5];
    const float* b_k   = (const float*)d_in[6];
    const float* w_v   = (const float*)d_in[7];
    const float* b_v   = (const float*)d_in[8];
    const float* w_o   = (const float*)d_in[9];
    const float* b_o   = (const float*)d_in[10];
    float* out = (float*)d_out;

    const int WN = D_MODEL * D_MODEL;                     // 262144
    const size_t plane = (size_t)BATCH * SEQ * D_MODEL;   // 4.19M halves

    _Float16* base = (_Float16*)d_ws;
    _Float16* Aq16 = base;                 // -> Oh after qkv
    _Float16* Ak16 = Aq16 + plane;
    _Float16* Av16 = Ak16 + plane;         // -> Op0 after qkv
    _Float16* whq  = Av16 + plane;
    _Float16* whk  = whq + WN;
    _Float16* whv  = whk + WN;
    _Float16* who  = whv + WN;
    _Float16* Qf   = who + WN;
    _Float16* Kf   = Qf + plane;
    _Float16* Vtf  = Kf + plane;
    _Float16* Op1  = Vtf + plane;
    float2*   Ml   = (float2*)(Op1 + plane);  // 2*BATCH*SEQ*NHEADS float2 = 1 MB
    _Float16* Oh   = Aq16;
    _Float16* Op0  = Av16;

    dim3 blk(256);

    hipLaunchKernelGGL(prep, dim3(3 * ABLK + 4 * WBLK), blk, 0, stream,
                       query, key, value, w_q, w_k, w_v, w_o,
                       Aq16, Ak16, Av16, whq, whk, whv, who);

    hipLaunchKernelGGL(gemm_qkv, dim3(D_MODEL / 128, BATCH * SEQ / 128, 3), blk, 0, stream,
                       Aq16, Ak16, Av16,
                       whq, whk, whv,
                       b_q, b_k, b_v, Qf, Kf, Vtf);

    hipLaunchKernelGGL(attn_mfma, dim3(NHEADS * BATCH * 2, SEQ / 128), blk, 0, stream,
                       Qf, Kf, Vtf, Op0, Op1, Ml);

    hipLaunchKernelGGL(attn_merge, dim3(BATCH * SEQ * D_MODEL / 4 / 256), blk, 0, stream,
                       Op0, Op1, Ml, Oh);

    hipLaunchKernelGGL(gemm_out, dim3(D_MODEL / 64, BATCH * SEQ / 128), blk, 0, stream,
                       Oh, who, b_o, out);
}